// Round 5
// baseline (156.333 us; speedup 1.0000x reference)
//
#include <hip/hip_runtime.h>
#include <hip/hip_bf16.h>
#include <hip/hip_fp16.h>

// deepSNN forward, layer_idx=3 path, element-sparse conv2.
// x:(20,6,160,160) w1:(30,6,4,4) w2:(250,30,3,3) w3:(200,250,3,3)
// pipeline: pad2->conv1->fire(1)->pool2x2 -> pad2->conv2->fire(1)->pool3x3
//           -> pad2->conv3->fire(25) -> out = [spk | pot] (2 x 20*200*29*29 fp32)
//
// r23: MEASUREMENT ROUND. r22's dense-MFMA conv2 regressed (+9.6us: A-build
// on 164/512 threads, 8-way A_lds bank conflicts, 3 serial phases) ->
// reverted to r21 sparse conv2 (best total 124.9us). conv1m's bf16 packing
// switched from emulated __float22bfloat162_rn (~6-8 VALU each) to the HW
// v_cvt_pk_bf16_f32 (1 VALU, identical RTE bits). k_conv1m is launched 3x
// (idempotent) to expose its true cost in the total:
//   conv1m ~= (total - 125) / 2   [duplicates removed next round]
// Component accounting is contradictory (delta-based: conv1m ~19-26us;
// instruction model: ~6-8us); this round settles it.
// r21: conv1m loads x directly (boundary-guarded); w2h pack in tail blocks.
// r20: conv2 fp16 oc-pair weights. r19: conv1 as bf16 MFMA implicit GEMM.

#define OUT_HALF 3364000  // 20*200*29*29
#define MASK_PLANE 128000 // 20*80*80 (u32 elements per plane)
#define T_FLOATS 168200   // 200*29*29 floats per t per half

typedef float f32x16 __attribute__((ext_vector_type(16)));
typedef short bf8s __attribute__((ext_vector_type(8)));
typedef float f32x4 __attribute__((ext_vector_type(4)));
typedef float v2f __attribute__((ext_vector_type(2)));
typedef f32x4 f32x4u __attribute__((aligned(4)));  // 4B-aligned vec4 load

// HW packed f32->bf16 RTE: dst.lo16 = bf16(a), dst.hi16 = bf16(b).
// (no builtin on gfx950; single VOP3 instruction, same bits as the
// emulated __float22bfloat162_rn path used through r21)
static __device__ __forceinline__ unsigned int cvtpk(float a, float b) {
    unsigned int r;
    asm("v_cvt_pk_bf16_f32 %0, %1, %2" : "=v"(r) : "v"(a), "v"(b));
    return r;
}
static __device__ __forceinline__ unsigned short bfbits(float a) {
    union { __hip_bfloat16 h; unsigned short u; } cv;
    cv.h = __float2bfloat16(a);
    return cv.u;
}
static __device__ __forceinline__ v2f up2(unsigned int u) {
    union { unsigned int u32; __half2 h2; } cv; cv.u32 = u;
    float2 f = __half22float2(cv.h2);
    v2f r; r.x = f.x; r.y = f.y;
    return r;
}
// interleave: bit k of v -> bit 2k
static __device__ __forceinline__ unsigned long long expand32(unsigned int v) {
    unsigned long long x = v;
    x = (x | (x << 16)) & 0x0000FFFF0000FFFFull;
    x = (x | (x << 8))  & 0x00FF00FF00FF00FFull;
    x = (x | (x << 4))  & 0x0F0F0F0F0F0F0F0Full;
    x = (x | (x << 2))  & 0x3333333333333333ull;
    x = (x | (x << 1))  & 0x5555555555555555ull;
    return x;
}

// ---------------- conv1 (bf16 MFMA) + fire(1) + pool2x2 -> mask1
//                  blocks 0..1999: conv1; 2000..2134: w2h pack + flags2 zero
// conv1 block b: t = b/100; wave unit u = (b%100)*4 + wave -> pr = u/5
// (pool row 0..79), jblk = u%5 (32 cols). Per wave: output rows 2pr (acc0),
// 2pr+1 (acc1), cols j0..j0+31, all 32 ocs (30 real + 2 zero).
// A-frag (ks slice = channel ks): lane(m=l&31,hi=l>>5) needs SOURCE rows
// (2pr+2hi-2)+{0,1,2} x cols (j-2)..(j+1); interior lanes use 3 float4
// loads, boundary lanes (j in {0,1,159} or row-edge) 12 guarded scalars.
// B staged once per block in LDS in fragment-linear order.
// C/D: col(oc)=lane&31, row(j-idx)=(reg&3)+8*(reg>>2)+4*hi  [verified map]
//  -> pool col p = (a&1) + 2*hi + 4*(a>>1) for reg pair (2a,2a+1).
__global__ __launch_bounds__(256) void k_conv1m(const float* __restrict__ x,
                                                const float* __restrict__ w1,
                                                const float* __restrict__ w2,
                                                unsigned int* __restrict__ w2h,
                                                unsigned int* __restrict__ mask1,
                                                unsigned int* __restrict__ flags2) {
    int tid = threadIdx.x;
    if (blockIdx.x >= 2000) {  // w2h[ck*128+pl] = pack(w2[2pl][ck], w2[2pl+1][ck])
        int tb = blockIdx.x - 2000;
        if (tb == 0)
            for (int i = tid; i < 540; i += 256) flags2[i] = 0u;
        int idx = tb * 256 + tid;  // < 135*256 = 34560 = 270*128 exactly
        int ck = idx >> 7, pl = idx & 127;
        int oc0 = 2 * pl, oc1 = oc0 + 1;
        float a = (oc0 < 250) ? w2[oc0 * 270 + ck] : 0.f;
        float bb = (oc1 < 250) ? w2[oc1 * 270 + ck] : 0.f;
        union { __half2 h2; unsigned int u; } cv;
        cv.h2.x = __float2half(a);
        cv.h2.y = __float2half(bb);
        w2h[idx] = cv.u;
        return;
    }

    __shared__ unsigned short B_lds[6 * 64 * 8];  // 6 KiB, frag-linear

    // stage B fragments: elem (ks, lane ll, i) at q=(ks*64+ll)*8+i
#pragma unroll
    for (int n = 0; n < 12; ++n) {
        int q = n * 256 + tid;
        int i = q & 7, ll = (q >> 3) & 63, ks = q >> 9;
        int oc = ll & 31;
        int kg = ks * 16 + ((ll >> 5) << 3) + i;
        float w = (oc < 30) ? w1[oc * 96 + kg] : 0.f;
        B_lds[q] = bfbits(w);
    }
    __syncthreads();

    int l = tid & 63, wv = tid >> 6;
    int b = blockIdx.x;
    int t = b / 100;
    int u = (b % 100) * 4 + wv;
    int pr = u / 5, jblk = u % 5;
    int m = l & 31, hi = l >> 5;
    int j = jblk * 32 + m;

    bf8s bq[6];
#pragma unroll
    for (int ks = 0; ks < 6; ++ks)
        bq[ks] = *(const bf8s*)&B_lds[(ks * 64 + l) * 8];

    f32x16 acc0 = (f32x16)(0.0f);
    f32x16 acc1 = (f32x16)(0.0f);
    int sr0 = 2 * pr + 2 * hi - 2;  // first SOURCE row needed by this lane
    int sc0 = j - 2;                // first SOURCE col
    bool fast = ((unsigned)sr0 <= 157u) && ((unsigned)sc0 <= 156u);

#pragma unroll
    for (int ks = 0; ks < 6; ++ks) {
        const float* xp = x + (t * 6 + ks) * 25600;
        f32x4 v0, v1, v2;
        if (fast) {
            const float* bp = xp + sr0 * 160 + sc0;
            v0 = *(const f32x4u*)(bp);
            v1 = *(const f32x4u*)(bp + 160);
            v2 = *(const f32x4u*)(bp + 320);
        } else {
            float tmp[3][4];
#pragma unroll
            for (int r = 0; r < 3; ++r)
#pragma unroll
                for (int e = 0; e < 4; ++e) {
                    int sr = sr0 + r, sc = sc0 + e;
                    tmp[r][e] = ((unsigned)sr < 160u && (unsigned)sc < 160u)
                                    ? xp[sr * 160 + sc] : 0.f;
                }
            v0.x = tmp[0][0]; v0.y = tmp[0][1]; v0.z = tmp[0][2]; v0.w = tmp[0][3];
            v1.x = tmp[1][0]; v1.y = tmp[1][1]; v1.z = tmp[1][2]; v1.w = tmp[1][3];
            v2.x = tmp[2][0]; v2.y = tmp[2][1]; v2.z = tmp[2][2]; v2.w = tmp[2][3];
        }
        union { bf8s s; unsigned int u4[4]; } a0, a1;
        a0.u4[0] = cvtpk(v0.x, v0.y);
        a0.u4[1] = cvtpk(v0.z, v0.w);
        a0.u4[2] = cvtpk(v1.x, v1.y);
        a0.u4[3] = cvtpk(v1.z, v1.w);
        a1.u4[0] = a0.u4[2];
        a1.u4[1] = a0.u4[3];
        a1.u4[2] = cvtpk(v2.x, v2.y);
        a1.u4[3] = cvtpk(v2.z, v2.w);
        acc0 = __builtin_amdgcn_mfma_f32_32x32x16_bf16(a0.s, bq[ks], acc0, 0, 0, 0);
        acc1 = __builtin_amdgcn_mfma_f32_32x32x16_bf16(a1.s, bq[ks], acc1, 0, 0, 0);
    }

    // fire(>1) + pool2x2 + pack 30 oc bits -> 3 mask planes of 10 bits
    unsigned int mbase = (unsigned int)((t * 80 + pr) * 80 + jblk * 16);
#pragma unroll
    for (int a = 0; a < 8; ++a) {
        bool s = acc0[2 * a] > 1.f || acc0[2 * a + 1] > 1.f ||
                 acc1[2 * a] > 1.f || acc1[2 * a + 1] > 1.f;
        unsigned long long bal = __ballot(s);
        if (l < 6) {
            int h = l >> 1;
            unsigned int word = (l & 1) ? (unsigned int)(bal >> 32)
                                        : (unsigned int)bal;
            int pc = (a & 1) + ((a >> 1) << 2) + ((l & 1) << 1);
            mask1[h * MASK_PLANE + mbase + pc] = (word >> (10 * h)) & 0x3FFu;
        }
    }
}

// ---------------- sparse conv2(3x3) + fire(1.0) + pool3x3 -> pool2m ballot
// block: (t, ph, 9 pw-ninths) = 4860 blocks, 256 thr = 4 waves.
// fp16 oc-pair weights: lane l of oc-half h owns ocs h*128+2l, h*128+2l+1;
// one u32 load = 128 ocs. Wave (h = wv&1, grp = wv>>1): grp0 walks windows
// (pwA, pwA+1) with the fused pair chain; grp1 walks pwA+2 solo (dual-spike).
// COMPILE-TIME (dr,ds) specialization kept. Ballots: even/odd-oc ballots
// bit-interleaved into the two 64-oc pool2m words of this half. flags2 set
// directly by firing waves (same-value multi-writer; visibility via kernel
// boundary) -- no tail barrier.
__global__ __launch_bounds__(256) void k_conv2(const unsigned int* __restrict__ mask1,
                                               const unsigned int* __restrict__ w2h,
                                               unsigned long long* __restrict__ pool2m,
                                               unsigned int* __restrict__ flags2) {
    __shared__ unsigned int m_lds[5 * 84];  // rows 3ph-2..3ph+2, cols -2..81

    int b = blockIdx.x;
    int ninth = b % 9;  b /= 9;
    int ph = b % 27;
    int t = b / 27;
    int tid = threadIdx.x;
    int l = tid & 63, wv = tid >> 6;
    int h = wv & 1, grp = wv >> 1;
    int r0 = 3 * ph - 2;
    int pwA = ninth * 3;

    for (int idx = tid; idx < 420; idx += 256) {
        int r = idx / 84, col = idx % 84;
        int gr = r0 + r, gc = col - 2;
        unsigned int v = 0;
        if ((unsigned)gr < 80u && (unsigned)gc < 80u) {
            int i2 = (t * 80 + gr) * 80 + gc;
            v = mask1[i2] | (mask1[MASK_PLANE + i2] << 10) |
                (mask1[2 * MASK_PLANE + i2] << 20);
        }
        m_lds[idx] = v;
    }
    __syncthreads();

    const unsigned int* wb = w2h + h * 64 + l;  // [ck][pl] stride 128
    unsigned long long* prow = pool2m + ((t * 27 + ph) * 27) * 4 + 2 * h;
    v2f z2 = (v2f)(0.f);

    if (grp == 0) {
        // ---- pw pair (pwA, pwA+1): interleaved gather chains ----
        int c0A = 3 * pwA, c0B = c0A + 3;
        unsigned int qA[25], qB[25];
#pragma unroll
        for (int dr = 0; dr < 5; ++dr)
#pragma unroll
            for (int ds = 0; ds < 5; ++ds) {
                qA[dr * 5 + ds] = m_lds[dr * 84 + c0A + ds];
                qB[dr * 5 + ds] = m_lds[dr * 84 + c0B + ds];
            }

        v2f accA[3][3], accB[3][3];
#pragma unroll
        for (int i = 0; i < 3; ++i)
#pragma unroll
            for (int j = 0; j < 3; ++j) { accA[i][j] = z2; accB[i][j] = z2; }

#pragma unroll
        for (int dr = 0; dr < 5; ++dr) {
#pragma unroll
            for (int ds = 0; ds < 5; ++ds) {
                unsigned int mA = qA[dr * 5 + ds];
                unsigned int mB = qB[dr * 5 + ds];
                while (mA | mB) {  // wave-uniform
                    bool hA = mA != 0, hB = mB != 0;
                    int cA = __builtin_ctz(mA | 0x40000000u);
                    int cB = __builtin_ctz(mB | 0x40000000u);
                    mA &= mA - 1;  // 0 stays 0
                    mB &= mB - 1;
                    const unsigned int* pA = wb + cA * 1152;  // c stride 9*128
                    const unsigned int* pB = wb + cB * 1152;
                    // both windows' loads issue together (independent)
                    unsigned int uA[3][3], uB[3][3];
#pragma unroll
                    for (int i = 0; i < 3; ++i) {
                        if (dr - i < 0 || dr - i > 2) continue;
#pragma unroll
                        for (int j = 0; j < 3; ++j) {
                            if (ds - j < 0 || ds - j > 2) continue;
                            int off = ((dr - i) * 3 + (ds - j)) * 128;
                            uA[i][j] = pA[off];
                            uB[i][j] = pB[off];
                        }
                    }
#pragma unroll
                    for (int i = 0; i < 3; ++i) {
                        if (dr - i < 0 || dr - i > 2) continue;
#pragma unroll
                        for (int j = 0; j < 3; ++j) {
                            if (ds - j < 0 || ds - j > 2) continue;
                            accA[i][j] += hA ? up2(uA[i][j]) : z2;
                            accB[i][j] += hB ? up2(uB[i][j]) : z2;
                        }
                    }
                }
            }
        }

        bool sA0 = false, sA1 = false, sB0 = false, sB1 = false;
#pragma unroll
        for (int i = 0; i < 3; ++i)
#pragma unroll
            for (int j = 0; j < 3; ++j) {
                sA0 = sA0 || (accA[i][j].x > 1.f);
                sA1 = sA1 || (accA[i][j].y > 1.f);
                sB0 = sB0 || (accB[i][j].x > 1.f);
                sB1 = sB1 || (accB[i][j].y > 1.f);
            }
        unsigned long long bA0 = __ballot(sA0), bA1 = __ballot(sA1);
        unsigned long long bB0 = __ballot(sB0), bB1 = __ballot(sB1);
        unsigned long long wA0 = expand32((unsigned int)bA0) |
                                 (expand32((unsigned int)bA1) << 1);
        unsigned long long wA1 = expand32((unsigned int)(bA0 >> 32)) |
                                 (expand32((unsigned int)(bA1 >> 32)) << 1);
        unsigned long long wB0 = expand32((unsigned int)bB0) |
                                 (expand32((unsigned int)bB1) << 1);
        unsigned long long wB1 = expand32((unsigned int)(bB0 >> 32)) |
                                 (expand32((unsigned int)(bB1 >> 32)) << 1);
        if (l == 0) {
            prow[pwA * 4]           = wA0;
            prow[pwA * 4 + 1]       = wA1;
            prow[(pwA + 1) * 4]     = wB0;
            prow[(pwA + 1) * 4 + 1] = wB1;
        }
        if ((wA0 | wA1 | wB0 | wB1) && l == 0)
            flags2[t * 27 + ph] = 1u;  // same-value multi-writer
    } else {
        // ---- solo pw (pwA+2), dual-spike walk ----
        int pw = pwA + 2;
        int c0 = 3 * pw;
        unsigned int q[25];
#pragma unroll
        for (int dr = 0; dr < 5; ++dr)
#pragma unroll
            for (int ds = 0; ds < 5; ++ds)
                q[dr * 5 + ds] = m_lds[dr * 84 + c0 + ds];

        v2f acc[3][3];
#pragma unroll
        for (int i = 0; i < 3; ++i)
#pragma unroll
            for (int j = 0; j < 3; ++j) acc[i][j] = z2;

#pragma unroll
        for (int dr = 0; dr < 5; ++dr) {
#pragma unroll
            for (int ds = 0; ds < 5; ++ds) {
                unsigned int m = q[dr * 5 + ds];
                while (m) {  // wave-uniform
                    int c1 = __builtin_ctz(m); m &= m - 1;
                    bool has2 = (m != 0);
                    int c2 = c1;
                    if (has2) { c2 = __builtin_ctz(m); m &= m - 1; }
                    const unsigned int* p1 = wb + c1 * 1152;
                    const unsigned int* p2 = wb + c2 * 1152;
                    unsigned int u1[3][3], u2[3][3];
#pragma unroll
                    for (int i = 0; i < 3; ++i) {
                        if (dr - i < 0 || dr - i > 2) continue;
#pragma unroll
                        for (int j = 0; j < 3; ++j) {
                            if (ds - j < 0 || ds - j > 2) continue;
                            int off = ((dr - i) * 3 + (ds - j)) * 128;
                            u1[i][j] = p1[off];
                            u2[i][j] = p2[off];
                        }
                    }
#pragma unroll
                    for (int i = 0; i < 3; ++i) {
                        if (dr - i < 0 || dr - i > 2) continue;
#pragma unroll
                        for (int j = 0; j < 3; ++j) {
                            if (ds - j < 0 || ds - j > 2) continue;
                            acc[i][j] += up2(u1[i][j]);
                            acc[i][j] += has2 ? up2(u2[i][j]) : z2;
                        }
                    }
                }
            }
        }

        bool s0 = false, s1 = false;
#pragma unroll
        for (int i = 0; i < 3; ++i)
#pragma unroll
            for (int j = 0; j < 3; ++j) {
                s0 = s0 || (acc[i][j].x > 1.f);
                s1 = s1 || (acc[i][j].y > 1.f);
            }
        unsigned long long b0 = __ballot(s0), b1 = __ballot(s1);
        unsigned long long w0 = expand32((unsigned int)b0) |
                                (expand32((unsigned int)b1) << 1);
        unsigned long long w1 = expand32((unsigned int)(b0 >> 32)) |
                                (expand32((unsigned int)(b1 >> 32)) << 1);
        if (l == 0) {
            prow[pw * 4]     = w0;
            prow[pw * 4 + 1] = w1;
        }
        if ((w0 | w1) && l == 0) flags2[t * 27 + ph] = 1u;
    }
}

// ---------------- conv3(3x3) + fire(25.0) -> out [spk|pot] (20,200,29,29) x2
// block: (t, 5 oc-groups of 40, 15 row-pairs), 320 thr = 40oc x 8 col-tiles(4)
// Fast path: all 27 flags of t clear -> whole t-image zeroed with contiguous
// float4 stores. Row-pair early-out and dense path kept for arbitrary inputs.
__global__ __launch_bounds__(320) void k_conv3(const unsigned long long* __restrict__ pool2m,
                                               const float* __restrict__ w3,
                                               float* __restrict__ out,
                                               const unsigned int* __restrict__ flags2) {
    __shared__ float w_lds[25 * 9 * 40];   // 9000 floats, [ck_local][ocl]
    __shared__ float in_lds[25 * 4 * 34];  // 3400 floats, [cl][r][col]

    int b = blockIdx.x;
    int rb = b % 15;  b /= 15;
    int ocg = b % 5;  b /= 5;
    int t = b;
    int oc0 = ocg * 40;
    int r0 = 2 * rb;  // output rows r0, r0+1
    int tid = threadIdx.x;
    int ocl = tid % 40, ct = tid / 40;  // ct in [0,8)

    // whole-t union of flags (wave-uniform scalar loads)
    {
        unsigned int fT = 0;
        const unsigned int* fp = flags2 + t * 27;
#pragma unroll
        for (int r = 0; r < 27; ++r) fT |= fp[r];
        if (fT == 0) {
            float4 z; z.x = 0.f; z.y = 0.f; z.z = 0.f; z.w = 0.f;
            float4* o0 = (float4*)(out + (size_t)t * T_FLOATS);
            float4* o1 = (float4*)(out + OUT_HALF + (size_t)t * T_FLOATS);
            int s = ocg * 15 + rb;           // slice id 0..74
            int lo = s * 561;                // 75*561 = 42075 >= 42050
            int hi = lo + 561; if (hi > 42050) hi = 42050;
            for (int i = lo + tid; i < hi; i += 320) {
                o0[i] = z;
                o1[i] = z;
            }
            return;
        }
    }

    // receptive field: pool2 rows r0-2..r0+1
    {
        unsigned int f = 0;
        int rlo = r0 - 2; if (rlo < 0) rlo = 0;
        int rhi = r0 + 1; if (rhi > 26) rhi = 26;
        for (int r = rlo; r <= rhi; ++r) f |= flags2[t * 27 + r];
        if (f == 0) {
            int nrows = (r0 + 1 < 29) ? 2 : 1;
            int stride = 29 * nrows;
            int cnt = 40 * stride;
            for (int idx = tid; idx < cnt; idx += 320) {
                int o = idx / stride, rem = idx % stride;
                size_t base = (size_t)((t * 200 + oc0 + o) * 29 + r0) * 29 + rem;
                out[base] = 0.f;
                out[OUT_HALF + base] = 0.f;
            }
            return;
        }
    }

    float acc[2][4];
#pragma unroll
    for (int i = 0; i < 2; ++i)
#pragma unroll
        for (int j = 0; j < 4; ++j) acc[i][j] = 0.f;

    for (int chn = 0; chn < 10; ++chn) {  // channel chunks of 25
        int cc0 = chn * 25;
        for (int idx = tid; idx < 25 * 9 * 40; idx += 320) {
            int o = idx % 40, ck = idx / 40;         // ck in [0,225)
            int ckg = cc0 * 9 + ck;                  // global (c,kh,kw) index
            w_lds[idx] = w3[(size_t)(oc0 + o) * 2250 + ckg];
        }
        for (int idx = tid; idx < 25 * 4 * 34; idx += 320) {
            int col = idx % 34;
            int rem = idx / 34;
            int r = rem & 3, cl = rem >> 2;
            int gr = r0 + r - 2, gc = col - 2;
            float v = 0.f;
            if ((unsigned)gr < 27u && (unsigned)gc < 27u) {
                int c = cc0 + cl;
                unsigned long long wbits =
                    pool2m[((t * 27 + gr) * 27 + gc) * 4 + (c >> 6)];
                v = (float)((wbits >> (c & 63)) & 1ull);
            }
            in_lds[idx] = v;
        }
        __syncthreads();

        for (int cl = 0; cl < 25; ++cl) {
            float in[4][6];
#pragma unroll
            for (int r = 0; r < 4; ++r)
#pragma unroll
                for (int j = 0; j < 6; ++j)
                    in[r][j] = in_lds[(cl * 4 + r) * 34 + ct * 4 + j];
            const float* wp = &w_lds[cl * 360 + ocl];
#pragma unroll
            for (int k = 0; k < 9; ++k) {
                float w = wp[k * 40];
                int kh = k / 3, kw = k % 3;
#pragma unroll
                for (int i = 0; i < 2; ++i)
#pragma unroll
                    for (int j = 0; j < 4; ++j)
                        acc[i][j] += in[i + kh][j + kw] * w;
            }
        }
        __syncthreads();
    }

    {
        int oc = oc0 + ocl;  // always < 200
#pragma unroll
        for (int i = 0; i < 2; ++i) {
            int r = r0 + i;
            if (r < 29) {
#pragma unroll
                for (int j = 0; j < 4; ++j) {
                    int col = ct * 4 + j;
                    if (col < 29) {
                        float pot = acc[i][j];
                        bool s = pot > 25.f;
                        size_t base = ((size_t)((t * 200 + oc) * 29 + r)) * 29 + col;
                        out[base] = s ? 1.f : 0.f;
                        out[OUT_HALF + base] = s ? pot : 0.f;
                    }
                }
            }
        }
    }
}

extern "C" void kernel_launch(void* const* d_in, const int* in_sizes, int n_in,
                              void* d_out, int out_size, void* d_ws, size_t ws_size,
                              hipStream_t stream) {
    const float* x  = (const float*)d_in[0];
    const float* w1 = (const float*)d_in[1];
    const float* w2 = (const float*)d_in[2];
    const float* w3 = (const float*)d_in[3];
    float* out = (float*)d_out;

    // workspace layout (bytes):
    //   mask1  u32: [0, 1,536,000)           3 planes x 20*80*80
    //   pool2m u64: [1,536,000, 2,002,560)   20*27*27*4 x 8B ballot words
    //   w2h    u32: [2,002,560, 2,140,800)   270x128 fp16 oc-pairs
    //   flags2    : [2,277,376, +2,160)      u32[20*27]
    unsigned int* mask1 = (unsigned int*)d_ws;
    unsigned long long* pool2m = (unsigned long long*)((char*)d_ws + 1536000);
    unsigned int* w2h = (unsigned int*)((char*)d_ws + 2002560);
    unsigned int* flags2 = (unsigned int*)((char*)d_ws + 2277376);

    // MEASUREMENT: k_conv1m launched 3x (idempotent -- pure function of
    // inputs; identical mask1/w2h/flags2 each run). conv1m ~= (total-125)/2.
    // Duplicates removed next round.
    k_conv1m<<<2135, 256, 0, stream>>>(x, w1, w2, w2h, mask1, flags2);
    k_conv1m<<<2135, 256, 0, stream>>>(x, w1, w2, w2h, mask1, flags2);
    k_conv1m<<<2135, 256, 0, stream>>>(x, w1, w2, w2h, mask1, flags2);
    k_conv2<<<20 * 27 * 9, 256, 0, stream>>>(mask1, w2h, pool2m, flags2);
    k_conv3<<<20 * 5 * 15, 320, 0, stream>>>(pool2m, w3, out, flags2);
}

// Round 6
// 120.309 us; speedup vs baseline: 1.2994x; 1.2994x over previous
//
#include <hip/hip_runtime.h>
#include <hip/hip_bf16.h>
#include <hip/hip_fp16.h>

// deepSNN forward, layer_idx=3 path, element-sparse conv2.
// x:(20,6,160,160) w1:(30,6,4,4) w2:(250,30,3,3) w3:(200,250,3,3)
// pipeline: pad2->conv1->fire(1)->pool2x2 -> pad2->conv2->fire(1)->pool3x3
//           -> pad2->conv3->fire(25) -> out = [spk | pot] (2 x 20*200*29*29 fp32)
//
// r24: conv1m restructured around LDS staging. r23 measured conv1m = 15.7us
// (3x-launch delta); cause: 12x redundant load+convert (147MB L1 traffic for
// a 12.8MB input; 48 cvt_pk/lane) + divergent boundary path on 40% of waves.
// New: block=(t,pr), 320thr; stage 5row x 164col x 6ch halo tile ONCE as
// bf16 in LDS, TWO pair-packed copies (E=(2k,2k+1), O=(2k+1,2k+2)) so lane
// col j reads its 4-wide window as 2 adjacent u32 from copy (j&1) at idx
// j>>1 -- no realign ops, no divergence; boundary zeros written in staging.
// Per K-step/lane: 6 LDS words + 2 MFMA (was 3 global float4 + 8 cvt_pk).
// mask1 bit-identical (same RTE converts, same MFMA).
// r23: conv1m measured via 3x launch (removed); HW v_cvt_pk_bf16_f32.
// r21: sparse conv2 (best known); w2h pack in tail blocks.
// r20: conv2 fp16 oc-pair weights. r19: conv1 as bf16 MFMA implicit GEMM.

#define OUT_HALF 3364000  // 20*200*29*29
#define MASK_PLANE 128000 // 20*80*80 (u32 elements per plane)
#define T_FLOATS 168200   // 200*29*29 floats per t per half

typedef float f32x16 __attribute__((ext_vector_type(16)));
typedef short bf8s __attribute__((ext_vector_type(8)));
typedef float f32x4 __attribute__((ext_vector_type(4)));
typedef float v2f __attribute__((ext_vector_type(2)));
typedef f32x4 f32x4u __attribute__((aligned(4)));  // 4B-aligned vec4 load

// HW packed f32->bf16 RTE: dst.lo16 = bf16(a), dst.hi16 = bf16(b).
static __device__ __forceinline__ unsigned int cvtpk(float a, float b) {
    unsigned int r;
    asm("v_cvt_pk_bf16_f32 %0, %1, %2" : "=v"(r) : "v"(a), "v"(b));
    return r;
}
static __device__ __forceinline__ unsigned short bfbits(float a) {
    union { __hip_bfloat16 h; unsigned short u; } cv;
    cv.h = __float2bfloat16(a);
    return cv.u;
}
static __device__ __forceinline__ v2f up2(unsigned int u) {
    union { unsigned int u32; __half2 h2; } cv; cv.u32 = u;
    float2 f = __half22float2(cv.h2);
    v2f r; r.x = f.x; r.y = f.y;
    return r;
}
// interleave: bit k of v -> bit 2k
static __device__ __forceinline__ unsigned long long expand32(unsigned int v) {
    unsigned long long x = v;
    x = (x | (x << 16)) & 0x0000FFFF0000FFFFull;
    x = (x | (x << 8))  & 0x00FF00FF00FF00FFull;
    x = (x | (x << 4))  & 0x0F0F0F0F0F0F0F0Full;
    x = (x | (x << 2))  & 0x3333333333333333ull;
    x = (x | (x << 1))  & 0x5555555555555555ull;
    return x;
}

// ---------------- conv1 (bf16 MFMA, LDS-staged) + fire(1) + pool2x2 -> mask1
//                  blocks 0..1599: conv1 (t=b/80, pr=b%80), 320 thr, 5 waves
//                  blocks 1600..1707: w2h pack + flags2 zero
// LDS xs[ch][copy][row][84] u32: row = local src row 0..4 (global 2pr-2+row),
//   copy0 (E) pair p = src cols (2p-2, 2p-1); copy1 (O) pair k = (2k-1, 2k).
//   OOB (row<0, row>159, col<0, col>159) staged as 0.
// Wave wv = jblk: output rows 2pr (acc0), 2pr+1 (acc1), cols j=32wv+m.
// Lane (m=l&31, hi=l>>5): A-frag rows = local 2hi+{0,1,2}, cols j-2..j+1 =
//   pairs a, a+1 of copy (j&1), a = j>>1.
// C/D: col(oc)=lane&31, row(j-idx)=(reg&3)+8*(reg>>2)+4*hi  [verified map]
__global__ __launch_bounds__(320) void k_conv1m(const float* __restrict__ x,
                                                const float* __restrict__ w1,
                                                const float* __restrict__ w2,
                                                unsigned int* __restrict__ w2h,
                                                unsigned int* __restrict__ mask1,
                                                unsigned int* __restrict__ flags2) {
    int tid = threadIdx.x;
    if (blockIdx.x >= 1600) {  // w2h[ck*128+pl] = pack(w2[2pl][ck], w2[2pl+1][ck])
        int tb = blockIdx.x - 1600;
        if (tb == 0)
            for (int i = tid; i < 540; i += 320) flags2[i] = 0u;
        int idx = tb * 320 + tid;  // 108*320 = 34560 = 270*128 exactly
        int ck = idx >> 7, pl = idx & 127;
        int oc0 = 2 * pl, oc1 = oc0 + 1;
        float a = (oc0 < 250) ? w2[oc0 * 270 + ck] : 0.f;
        float bb = (oc1 < 250) ? w2[oc1 * 270 + ck] : 0.f;
        union { __half2 h2; unsigned int u; } cv;
        cv.h2.x = __float2half(a);
        cv.h2.y = __float2half(bb);
        w2h[idx] = cv.u;
        return;
    }

    __shared__ unsigned int xs[6 * 10 * 84];      // 20160 B  [ch][copy*5+row][84]
    __shared__ unsigned short B_lds[6 * 64 * 8];  // 6144 B, frag-linear

    int b = blockIdx.x;
    int pr = b % 80, t = b / 80;

    // ---- stage B fragments (w1 -> bf16, frag-linear)
    for (int q = tid; q < 3072; q += 320) {
        int i = q & 7, ll = (q >> 3) & 63, ks = q >> 9;
        int oc = ll & 31;
        int kg = ks * 16 + ((ll >> 5) << 3) + i;
        float w = (oc < 30) ? w1[oc * 96 + kg] : 0.f;
        B_lds[q] = bfbits(w);
    }

    // ---- stage x tile: rows 2pr-2..2pr+2, cols -2..161, 6 ch, E+O copies
    // boundary pairs p=0 (E: cols -2,-1 -> 0; O: cols -1,0 -> (0, x[sr][0]))
    if (tid < 30) {
        int ch = tid / 5, r = tid % 5;
        int sr = 2 * pr - 2 + r;
        float x0 = ((unsigned)sr < 160u) ? x[((t * 6 + ch) * 160 + sr) * 160] : 0.f;
        xs[(ch * 10 + r) * 84] = 0u;
        xs[(ch * 10 + 5 + r) * 84] = cvtpk(0.f, x0);
    }
    // main pairs: unit u = (ch,row)*40 + q; float4 = src cols 4q..4q+3
#pragma unroll
    for (int n = 0; n < 4; ++n) {
        int u = n * 320 + tid;
        if (u >= 1200) break;
        int q = u % 40, combo = u / 40;
        int ch = combo / 5, r = combo % 5;
        int sr = 2 * pr - 2 + r;
        const float* xp = x + ((t * 6 + ch) * 160 + sr) * 160;
        f32x4 f; f.x = 0.f; f.y = 0.f; f.z = 0.f; f.w = 0.f;
        bool inr = (unsigned)sr < 160u;
        if (inr) f = *(const f32x4u*)(xp + 4 * q);
        float nx = __shfl_down(f.x, 1);           // neighbor's col 4q+4
        if ((tid & 63) == 63 && q != 39)          // cross-wave neighbor
            nx = inr ? xp[4 * q + 4] : 0.f;
        if (q == 39) nx = 0.f;                    // col 160 is padding
        unsigned int e0 = cvtpk(f.x, f.y), e1 = cvtpk(f.z, f.w);
        unsigned int o0 = cvtpk(f.y, f.z), o1 = cvtpk(f.w, nx);
        unsigned int baseE = (unsigned)(ch * 10 + r) * 84 + 2 * q + 1;
        unsigned int baseO = (unsigned)(ch * 10 + 5 + r) * 84 + 2 * q + 1;
        xs[baseE] = e0; xs[baseE + 1] = e1;
        xs[baseO] = o0; xs[baseO + 1] = o1;
    }
    __syncthreads();

    int l = tid & 63, wv = tid >> 6;
    int m = l & 31, hi = l >> 5;
    int j = wv * 32 + m;
    int a = j >> 1, par = j & 1;

    bf8s bq[6];
#pragma unroll
    for (int ks = 0; ks < 6; ++ks)
        bq[ks] = *(const bf8s*)&B_lds[(ks * 64 + l) * 8];

    f32x16 acc0 = (f32x16)(0.0f);
    f32x16 acc1 = (f32x16)(0.0f);
    unsigned int bidx0 = (unsigned)(par * 5 + 2 * hi) * 84 + a;

#pragma unroll
    for (int ks = 0; ks < 6; ++ks) {
        unsigned int bidx = bidx0 + (unsigned)ks * 840;
        unsigned int r00 = xs[bidx],       r01 = xs[bidx + 1];
        unsigned int r10 = xs[bidx + 84],  r11 = xs[bidx + 85];
        unsigned int r20 = xs[bidx + 168], r21 = xs[bidx + 169];
        union { bf8s s; unsigned int u4[4]; } a0, a1;
        a0.u4[0] = r00; a0.u4[1] = r01; a0.u4[2] = r10; a0.u4[3] = r11;
        a1.u4[0] = r10; a1.u4[1] = r11; a1.u4[2] = r20; a1.u4[3] = r21;
        acc0 = __builtin_amdgcn_mfma_f32_32x32x16_bf16(a0.s, bq[ks], acc0, 0, 0, 0);
        acc1 = __builtin_amdgcn_mfma_f32_32x32x16_bf16(a1.s, bq[ks], acc1, 0, 0, 0);
    }

    // fire(>1) + pool2x2 + pack 30 oc bits -> 3 mask planes of 10 bits
    unsigned int mbase = (unsigned int)((t * 80 + pr) * 80 + wv * 16);
#pragma unroll
    for (int aa = 0; aa < 8; ++aa) {
        bool s = acc0[2 * aa] > 1.f || acc0[2 * aa + 1] > 1.f ||
                 acc1[2 * aa] > 1.f || acc1[2 * aa + 1] > 1.f;
        unsigned long long bal = __ballot(s);
        if (l < 6) {
            int h = l >> 1;
            unsigned int word = (l & 1) ? (unsigned int)(bal >> 32)
                                        : (unsigned int)bal;
            int pc = (aa & 1) + ((aa >> 1) << 2) + ((l & 1) << 1);
            mask1[h * MASK_PLANE + mbase + pc] = (word >> (10 * h)) & 0x3FFu;
        }
    }
}

// ---------------- sparse conv2(3x3) + fire(1.0) + pool3x3 -> pool2m ballot
// block: (t, ph, 9 pw-ninths) = 4860 blocks, 256 thr = 4 waves.
// fp16 oc-pair weights: lane l of oc-half h owns ocs h*128+2l, h*128+2l+1;
// one u32 load = 128 ocs. Wave (h = wv&1, grp = wv>>1): grp0 walks windows
// (pwA, pwA+1) with the fused pair chain; grp1 walks pwA+2 solo (dual-spike).
__global__ __launch_bounds__(256) void k_conv2(const unsigned int* __restrict__ mask1,
                                               const unsigned int* __restrict__ w2h,
                                               unsigned long long* __restrict__ pool2m,
                                               unsigned int* __restrict__ flags2) {
    __shared__ unsigned int m_lds[5 * 84];  // rows 3ph-2..3ph+2, cols -2..81

    int b = blockIdx.x;
    int ninth = b % 9;  b /= 9;
    int ph = b % 27;
    int t = b / 27;
    int tid = threadIdx.x;
    int l = tid & 63, wv = tid >> 6;
    int h = wv & 1, grp = wv >> 1;
    int r0 = 3 * ph - 2;
    int pwA = ninth * 3;

    for (int idx = tid; idx < 420; idx += 256) {
        int r = idx / 84, col = idx % 84;
        int gr = r0 + r, gc = col - 2;
        unsigned int v = 0;
        if ((unsigned)gr < 80u && (unsigned)gc < 80u) {
            int i2 = (t * 80 + gr) * 80 + gc;
            v = mask1[i2] | (mask1[MASK_PLANE + i2] << 10) |
                (mask1[2 * MASK_PLANE + i2] << 20);
        }
        m_lds[idx] = v;
    }
    __syncthreads();

    const unsigned int* wb = w2h + h * 64 + l;  // [ck][pl] stride 128
    unsigned long long* prow = pool2m + ((t * 27 + ph) * 27) * 4 + 2 * h;
    v2f z2 = (v2f)(0.f);

    if (grp == 0) {
        // ---- pw pair (pwA, pwA+1): interleaved gather chains ----
        int c0A = 3 * pwA, c0B = c0A + 3;
        unsigned int qA[25], qB[25];
#pragma unroll
        for (int dr = 0; dr < 5; ++dr)
#pragma unroll
            for (int ds = 0; ds < 5; ++ds) {
                qA[dr * 5 + ds] = m_lds[dr * 84 + c0A + ds];
                qB[dr * 5 + ds] = m_lds[dr * 84 + c0B + ds];
            }

        v2f accA[3][3], accB[3][3];
#pragma unroll
        for (int i = 0; i < 3; ++i)
#pragma unroll
            for (int j = 0; j < 3; ++j) { accA[i][j] = z2; accB[i][j] = z2; }

#pragma unroll
        for (int dr = 0; dr < 5; ++dr) {
#pragma unroll
            for (int ds = 0; ds < 5; ++ds) {
                unsigned int mA = qA[dr * 5 + ds];
                unsigned int mB = qB[dr * 5 + ds];
                while (mA | mB) {  // wave-uniform
                    bool hA = mA != 0, hB = mB != 0;
                    int cA = __builtin_ctz(mA | 0x40000000u);
                    int cB = __builtin_ctz(mB | 0x40000000u);
                    mA &= mA - 1;  // 0 stays 0
                    mB &= mB - 1;
                    const unsigned int* pA = wb + cA * 1152;  // c stride 9*128
                    const unsigned int* pB = wb + cB * 1152;
                    unsigned int uA[3][3], uB[3][3];
#pragma unroll
                    for (int i = 0; i < 3; ++i) {
                        if (dr - i < 0 || dr - i > 2) continue;
#pragma unroll
                        for (int j = 0; j < 3; ++j) {
                            if (ds - j < 0 || ds - j > 2) continue;
                            int off = ((dr - i) * 3 + (ds - j)) * 128;
                            uA[i][j] = pA[off];
                            uB[i][j] = pB[off];
                        }
                    }
#pragma unroll
                    for (int i = 0; i < 3; ++i) {
                        if (dr - i < 0 || dr - i > 2) continue;
#pragma unroll
                        for (int j = 0; j < 3; ++j) {
                            if (ds - j < 0 || ds - j > 2) continue;
                            accA[i][j] += hA ? up2(uA[i][j]) : z2;
                            accB[i][j] += hB ? up2(uB[i][j]) : z2;
                        }
                    }
                }
            }
        }

        bool sA0 = false, sA1 = false, sB0 = false, sB1 = false;
#pragma unroll
        for (int i = 0; i < 3; ++i)
#pragma unroll
            for (int j = 0; j < 3; ++j) {
                sA0 = sA0 || (accA[i][j].x > 1.f);
                sA1 = sA1 || (accA[i][j].y > 1.f);
                sB0 = sB0 || (accB[i][j].x > 1.f);
                sB1 = sB1 || (accB[i][j].y > 1.f);
            }
        unsigned long long bA0 = __ballot(sA0), bA1 = __ballot(sA1);
        unsigned long long bB0 = __ballot(sB0), bB1 = __ballot(sB1);
        unsigned long long wA0 = expand32((unsigned int)bA0) |
                                 (expand32((unsigned int)bA1) << 1);
        unsigned long long wA1 = expand32((unsigned int)(bA0 >> 32)) |
                                 (expand32((unsigned int)(bA1 >> 32)) << 1);
        unsigned long long wB0 = expand32((unsigned int)bB0) |
                                 (expand32((unsigned int)bB1) << 1);
        unsigned long long wB1 = expand32((unsigned int)(bB0 >> 32)) |
                                 (expand32((unsigned int)(bB1 >> 32)) << 1);
        if (l == 0) {
            prow[pwA * 4]           = wA0;
            prow[pwA * 4 + 1]       = wA1;
            prow[(pwA + 1) * 4]     = wB0;
            prow[(pwA + 1) * 4 + 1] = wB1;
        }
        if ((wA0 | wA1 | wB0 | wB1) && l == 0)
            flags2[t * 27 + ph] = 1u;  // same-value multi-writer
    } else {
        // ---- solo pw (pwA+2), dual-spike walk ----
        int pw = pwA + 2;
        int c0 = 3 * pw;
        unsigned int q[25];
#pragma unroll
        for (int dr = 0; dr < 5; ++dr)
#pragma unroll
            for (int ds = 0; ds < 5; ++ds)
                q[dr * 5 + ds] = m_lds[dr * 84 + c0 + ds];

        v2f acc[3][3];
#pragma unroll
        for (int i = 0; i < 3; ++i)
#pragma unroll
            for (int j = 0; j < 3; ++j) acc[i][j] = z2;

#pragma unroll
        for (int dr = 0; dr < 5; ++dr) {
#pragma unroll
            for (int ds = 0; ds < 5; ++ds) {
                unsigned int m = q[dr * 5 + ds];
                while (m) {  // wave-uniform
                    int c1 = __builtin_ctz(m); m &= m - 1;
                    bool has2 = (m != 0);
                    int c2 = c1;
                    if (has2) { c2 = __builtin_ctz(m); m &= m - 1; }
                    const unsigned int* p1 = wb + c1 * 1152;
                    const unsigned int* p2 = wb + c2 * 1152;
                    unsigned int u1[3][3], u2[3][3];
#pragma unroll
                    for (int i = 0; i < 3; ++i) {
                        if (dr - i < 0 || dr - i > 2) continue;
#pragma unroll
                        for (int j = 0; j < 3; ++j) {
                            if (ds - j < 0 || ds - j > 2) continue;
                            int off = ((dr - i) * 3 + (ds - j)) * 128;
                            u1[i][j] = p1[off];
                            u2[i][j] = p2[off];
                        }
                    }
#pragma unroll
                    for (int i = 0; i < 3; ++i) {
                        if (dr - i < 0 || dr - i > 2) continue;
#pragma unroll
                        for (int j = 0; j < 3; ++j) {
                            if (ds - j < 0 || ds - j > 2) continue;
                            acc[i][j] += up2(u1[i][j]);
                            acc[i][j] += has2 ? up2(u2[i][j]) : z2;
                        }
                    }
                }
            }
        }

        bool s0 = false, s1 = false;
#pragma unroll
        for (int i = 0; i < 3; ++i)
#pragma unroll
            for (int j = 0; j < 3; ++j) {
                s0 = s0 || (acc[i][j].x > 1.f);
                s1 = s1 || (acc[i][j].y > 1.f);
            }
        unsigned long long b0 = __ballot(s0), b1 = __ballot(s1);
        unsigned long long w0 = expand32((unsigned int)b0) |
                                (expand32((unsigned int)b1) << 1);
        unsigned long long w1 = expand32((unsigned int)(b0 >> 32)) |
                                (expand32((unsigned int)(b1 >> 32)) << 1);
        if (l == 0) {
            prow[pw * 4]     = w0;
            prow[pw * 4 + 1] = w1;
        }
        if ((w0 | w1) && l == 0) flags2[t * 27 + ph] = 1u;
    }
}

// ---------------- conv3(3x3) + fire(25.0) -> out [spk|pot] (20,200,29,29) x2
__global__ __launch_bounds__(320) void k_conv3(const unsigned long long* __restrict__ pool2m,
                                               const float* __restrict__ w3,
                                               float* __restrict__ out,
                                               const unsigned int* __restrict__ flags2) {
    __shared__ float w_lds[25 * 9 * 40];   // 9000 floats, [ck_local][ocl]
    __shared__ float in_lds[25 * 4 * 34];  // 3400 floats, [cl][r][col]

    int b = blockIdx.x;
    int rb = b % 15;  b /= 15;
    int ocg = b % 5;  b /= 5;
    int t = b;
    int oc0 = ocg * 40;
    int r0 = 2 * rb;  // output rows r0, r0+1
    int tid = threadIdx.x;
    int ocl = tid % 40, ct = tid / 40;  // ct in [0,8)

    // whole-t union of flags (wave-uniform scalar loads)
    {
        unsigned int fT = 0;
        const unsigned int* fp = flags2 + t * 27;
#pragma unroll
        for (int r = 0; r < 27; ++r) fT |= fp[r];
        if (fT == 0) {
            float4 z; z.x = 0.f; z.y = 0.f; z.z = 0.f; z.w = 0.f;
            float4* o0 = (float4*)(out + (size_t)t * T_FLOATS);
            float4* o1 = (float4*)(out + OUT_HALF + (size_t)t * T_FLOATS);
            int s = ocg * 15 + rb;           // slice id 0..74
            int lo = s * 561;                // 75*561 = 42075 >= 42050
            int hi = lo + 561; if (hi > 42050) hi = 42050;
            for (int i = lo + tid; i < hi; i += 320) {
                o0[i] = z;
                o1[i] = z;
            }
            return;
        }
    }

    // receptive field: pool2 rows r0-2..r0+1
    {
        unsigned int f = 0;
        int rlo = r0 - 2; if (rlo < 0) rlo = 0;
        int rhi = r0 + 1; if (rhi > 26) rhi = 26;
        for (int r = rlo; r <= rhi; ++r) f |= flags2[t * 27 + r];
        if (f == 0) {
            int nrows = (r0 + 1 < 29) ? 2 : 1;
            int stride = 29 * nrows;
            int cnt = 40 * stride;
            for (int idx = tid; idx < cnt; idx += 320) {
                int o = idx / stride, rem = idx % stride;
                size_t base = (size_t)((t * 200 + oc0 + o) * 29 + r0) * 29 + rem;
                out[base] = 0.f;
                out[OUT_HALF + base] = 0.f;
            }
            return;
        }
    }

    float acc[2][4];
#pragma unroll
    for (int i = 0; i < 2; ++i)
#pragma unroll
        for (int j = 0; j < 4; ++j) acc[i][j] = 0.f;

    for (int chn = 0; chn < 10; ++chn) {  // channel chunks of 25
        int cc0 = chn * 25;
        for (int idx = tid; idx < 25 * 9 * 40; idx += 320) {
            int o = idx % 40, ck = idx / 40;         // ck in [0,225)
            int ckg = cc0 * 9 + ck;                  // global (c,kh,kw) index
            w_lds[idx] = w3[(size_t)(oc0 + o) * 2250 + ckg];
        }
        for (int idx = tid; idx < 25 * 4 * 34; idx += 320) {
            int col = idx % 34;
            int rem = idx / 34;
            int r = rem & 3, cl = rem >> 2;
            int gr = r0 + r - 2, gc = col - 2;
            float v = 0.f;
            if ((unsigned)gr < 27u && (unsigned)gc < 27u) {
                int c = cc0 + cl;
                unsigned long long wbits =
                    pool2m[((t * 27 + gr) * 27 + gc) * 4 + (c >> 6)];
                v = (float)((wbits >> (c & 63)) & 1ull);
            }
            in_lds[idx] = v;
        }
        __syncthreads();

        for (int cl = 0; cl < 25; ++cl) {
            float in[4][6];
#pragma unroll
            for (int r = 0; r < 4; ++r)
#pragma unroll
                for (int j = 0; j < 6; ++j)
                    in[r][j] = in_lds[(cl * 4 + r) * 34 + ct * 4 + j];
            const float* wp = &w_lds[cl * 360 + ocl];
#pragma unroll
            for (int k = 0; k < 9; ++k) {
                float w = wp[k * 40];
                int kh = k / 3, kw = k % 3;
#pragma unroll
                for (int i = 0; i < 2; ++i)
#pragma unroll
                    for (int j = 0; j < 4; ++j)
                        acc[i][j] += in[i + kh][j + kw] * w;
            }
        }
        __syncthreads();
    }

    {
        int oc = oc0 + ocl;  // always < 200
#pragma unroll
        for (int i = 0; i < 2; ++i) {
            int r = r0 + i;
            if (r < 29) {
#pragma unroll
                for (int j = 0; j < 4; ++j) {
                    int col = ct * 4 + j;
                    if (col < 29) {
                        float pot = acc[i][j];
                        bool s = pot > 25.f;
                        size_t base = ((size_t)((t * 200 + oc) * 29 + r)) * 29 + col;
                        out[base] = s ? 1.f : 0.f;
                        out[OUT_HALF + base] = s ? pot : 0.f;
                    }
                }
            }
        }
    }
}

extern "C" void kernel_launch(void* const* d_in, const int* in_sizes, int n_in,
                              void* d_out, int out_size, void* d_ws, size_t ws_size,
                              hipStream_t stream) {
    const float* x  = (const float*)d_in[0];
    const float* w1 = (const float*)d_in[1];
    const float* w2 = (const float*)d_in[2];
    const float* w3 = (const float*)d_in[3];
    float* out = (float*)d_out;

    // workspace layout (bytes):
    //   mask1  u32: [0, 1,536,000)           3 planes x 20*80*80
    //   pool2m u64: [1,536,000, 2,002,560)   20*27*27*4 x 8B ballot words
    //   w2h    u32: [2,002,560, 2,140,800)   270x128 fp16 oc-pairs
    //   flags2    : [2,277,376, +2,160)      u32[20*27]
    unsigned int* mask1 = (unsigned int*)d_ws;
    unsigned long long* pool2m = (unsigned long long*)((char*)d_ws + 1536000);
    unsigned int* w2h = (unsigned int*)((char*)d_ws + 2002560);
    unsigned int* flags2 = (unsigned int*)((char*)d_ws + 2277376);

    // blocks 0..1599: conv1 (LDS-staged MFMA); 1600..1707: w2h pack + flags2
    k_conv1m<<<1708, 320, 0, stream>>>(x, w1, w2, w2h, mask1, flags2);
    k_conv2<<<20 * 27 * 9, 256, 0, stream>>>(mask1, w2h, pool2m, flags2);
    k_conv3<<<20 * 5 * 15, 320, 0, stream>>>(pool2m, w3, out, flags2);
}

// Round 8
// 115.245 us; speedup vs baseline: 1.3565x; 1.0439x over previous
//
#include <hip/hip_runtime.h>
#include <hip/hip_bf16.h>
#include <hip/hip_fp16.h>

// deepSNN forward, layer_idx=3 path, element-sparse conv2.
// x:(20,6,160,160) w1:(30,6,4,4) w2:(250,30,3,3) w3:(200,250,3,3)
// pipeline: pad2->conv1->fire(1)->pool2x2 -> pad2->conv2->fire(1)->pool3x3
//           -> pad2->conv3->fire(25) -> out = [spk | pot] (2 x 20*200*29*29 fp32)
//
// r26 = r25 resubmit (bench infra failed twice; no kernel signal).
// r25: conv2 inner-loop VALU cut ~4x, walk structure preserved. Old per-tap
// cost: cndmask + 2x cvt_f32_f16 + 2x add_f32 (~5-7 VALU). New: accumulate
// fp16 pairs directly with v_pk_add_f16 (1 VALU/tap) and replace the
// hA/hB/has2 selects with a ZERO-WEIGHT SENTINEL: ctz(empty|bit30)=30 ->
// wb+30*1152 lands in a zeroed pad of w2h ([34560,35712) zero-filled in the
// pack tail) -> unconditional adds. fp16 accum error (~0.01 over <=40 terms)
// << measured >=0.6 margin to threshold 1.0 -> spike set / flags2 / output
// invariant; absmax stays 0.0 exactly.
// r24: conv1m LDS-staged (15.7 -> ~11us). r23: conv1m cost measured via 3x
// launch. r21: direct-x loads, w2h pack in tail. r19: conv1 bf16 MFMA.

#define OUT_HALF 3364000  // 20*200*29*29
#define MASK_PLANE 128000 // 20*80*80 (u32 elements per plane)
#define T_FLOATS 168200   // 200*29*29 floats per t per half

typedef float f32x16 __attribute__((ext_vector_type(16)));
typedef short bf8s __attribute__((ext_vector_type(8)));
typedef float f32x4 __attribute__((ext_vector_type(4)));
typedef f32x4 f32x4u __attribute__((aligned(4)));  // 4B-aligned vec4 load

// HW packed f32->bf16 RTE: dst.lo16 = bf16(a), dst.hi16 = bf16(b).
static __device__ __forceinline__ unsigned int cvtpk(float a, float b) {
    unsigned int r;
    asm("v_cvt_pk_bf16_f32 %0, %1, %2" : "=v"(r) : "v"(a), "v"(b));
    return r;
}
static __device__ __forceinline__ unsigned short bfbits(float a) {
    union { __hip_bfloat16 h; unsigned short u; } cv;
    cv.h = __float2bfloat16(a);
    return cv.u;
}
static __device__ __forceinline__ __half2 bch2(unsigned int u) {
    union { unsigned int u32; __half2 h2; } cv; cv.u32 = u;
    return cv.h2;
}
// interleave: bit k of v -> bit 2k
static __device__ __forceinline__ unsigned long long expand32(unsigned int v) {
    unsigned long long x = v;
    x = (x | (x << 16)) & 0x0000FFFF0000FFFFull;
    x = (x | (x << 8))  & 0x00FF00FF00FF00FFull;
    x = (x | (x << 4))  & 0x0F0F0F0F0F0F0F0Full;
    x = (x | (x << 2))  & 0x3333333333333333ull;
    x = (x | (x << 1))  & 0x5555555555555555ull;
    return x;
}

// ---------------- conv1 (bf16 MFMA, LDS-staged) + fire(1) + pool2x2 -> mask1
//                  blocks 0..1599: conv1 (t=b/80, pr=b%80), 320 thr, 5 waves
//                  blocks 1600..1711: w2h pack (+ zero sentinel pad) + flags2
// LDS xs[ch][copy][row][84] u32: row = local src row 0..4 (global 2pr-2+row),
//   copy0 (E) pair p = src cols (2p-2, 2p-1); copy1 (O) pair k = (2k-1, 2k).
//   OOB staged as 0. Wave wv = jblk: output rows 2pr (acc0), 2pr+1 (acc1),
//   cols j=32wv+m. Lane (m=l&31, hi=l>>5): A-frag rows local 2hi+{0,1,2},
//   cols j-2..j+1 = pairs a, a+1 of copy (j&1), a = j>>1.
// C/D: col(oc)=lane&31, row(j-idx)=(reg&3)+8*(reg>>2)+4*hi  [verified map]
__global__ __launch_bounds__(320) void k_conv1m(const float* __restrict__ x,
                                                const float* __restrict__ w1,
                                                const float* __restrict__ w2,
                                                unsigned int* __restrict__ w2h,
                                                unsigned int* __restrict__ mask1,
                                                unsigned int* __restrict__ flags2) {
    int tid = threadIdx.x;
    if (blockIdx.x >= 1600) {  // w2h[ck*128+pl] = pack(w2[2pl][ck], w2[2pl+1][ck])
        int tb = blockIdx.x - 1600;
        if (tb == 0)
            for (int i = tid; i < 540; i += 320) flags2[i] = 0u;
        int idx = tb * 320 + tid;  // < 112*320 = 35840
        if (idx < 35712) {         // [34560,35712) = zero sentinel region (c=30)
            unsigned int val = 0u;
            if (idx < 34560) {
                int ck = idx >> 7, pl = idx & 127;
                int oc0 = 2 * pl, oc1 = oc0 + 1;
                float a = (oc0 < 250) ? w2[oc0 * 270 + ck] : 0.f;
                float bb = (oc1 < 250) ? w2[oc1 * 270 + ck] : 0.f;
                union { __half2 h2; unsigned int u; } cv;
                cv.h2.x = __float2half(a);
                cv.h2.y = __float2half(bb);
                val = cv.u;
            }
            w2h[idx] = val;
        }
        return;
    }

    __shared__ unsigned int xs[6 * 10 * 84];      // 20160 B  [ch][copy*5+row][84]
    __shared__ unsigned short B_lds[6 * 64 * 8];  // 6144 B, frag-linear

    int b = blockIdx.x;
    int pr = b % 80, t = b / 80;

    // ---- stage B fragments (w1 -> bf16, frag-linear)
    for (int q = tid; q < 3072; q += 320) {
        int i = q & 7, ll = (q >> 3) & 63, ks = q >> 9;
        int oc = ll & 31;
        int kg = ks * 16 + ((ll >> 5) << 3) + i;
        float w = (oc < 30) ? w1[oc * 96 + kg] : 0.f;
        B_lds[q] = bfbits(w);
    }

    // ---- stage x tile: rows 2pr-2..2pr+2, cols -2..161, 6 ch, E+O copies
    if (tid < 30) {
        int ch = tid / 5, r = tid % 5;
        int sr = 2 * pr - 2 + r;
        float x0 = ((unsigned)sr < 160u) ? x[((t * 6 + ch) * 160 + sr) * 160] : 0.f;
        xs[(ch * 10 + r) * 84] = 0u;
        xs[(ch * 10 + 5 + r) * 84] = cvtpk(0.f, x0);
    }
    // main pairs: unit u = (ch,row)*40 + q; float4 = src cols 4q..4q+3
#pragma unroll
    for (int n = 0; n < 4; ++n) {
        int u = n * 320 + tid;
        if (u >= 1200) break;
        int q = u % 40, combo = u / 40;
        int ch = combo / 5, r = combo % 5;
        int sr = 2 * pr - 2 + r;
        const float* xp = x + ((t * 6 + ch) * 160 + sr) * 160;
        f32x4 f; f.x = 0.f; f.y = 0.f; f.z = 0.f; f.w = 0.f;
        bool inr = (unsigned)sr < 160u;
        if (inr) f = *(const f32x4u*)(xp + 4 * q);
        float nx = __shfl_down(f.x, 1);           // neighbor's col 4q+4
        if ((tid & 63) == 63 && q != 39)          // cross-wave neighbor
            nx = inr ? xp[4 * q + 4] : 0.f;
        if (q == 39) nx = 0.f;                    // col 160 is padding
        unsigned int e0 = cvtpk(f.x, f.y), e1 = cvtpk(f.z, f.w);
        unsigned int o0 = cvtpk(f.y, f.z), o1 = cvtpk(f.w, nx);
        unsigned int baseE = (unsigned)(ch * 10 + r) * 84 + 2 * q + 1;
        unsigned int baseO = (unsigned)(ch * 10 + 5 + r) * 84 + 2 * q + 1;
        xs[baseE] = e0; xs[baseE + 1] = e1;
        xs[baseO] = o0; xs[baseO + 1] = o1;
    }
    __syncthreads();

    int l = tid & 63, wv = tid >> 6;
    int m = l & 31, hi = l >> 5;
    int j = wv * 32 + m;
    int a = j >> 1, par = j & 1;

    bf8s bq[6];
#pragma unroll
    for (int ks = 0; ks < 6; ++ks)
        bq[ks] = *(const bf8s*)&B_lds[(ks * 64 + l) * 8];

    f32x16 acc0 = (f32x16)(0.0f);
    f32x16 acc1 = (f32x16)(0.0f);
    unsigned int bidx0 = (unsigned)(par * 5 + 2 * hi) * 84 + a;

#pragma unroll
    for (int ks = 0; ks < 6; ++ks) {
        unsigned int bidx = bidx0 + (unsigned)ks * 840;
        unsigned int r00 = xs[bidx],       r01 = xs[bidx + 1];
        unsigned int r10 = xs[bidx + 84],  r11 = xs[bidx + 85];
        unsigned int r20 = xs[bidx + 168], r21 = xs[bidx + 169];
        union { bf8s s; unsigned int u4[4]; } a0, a1;
        a0.u4[0] = r00; a0.u4[1] = r01; a0.u4[2] = r10; a0.u4[3] = r11;
        a1.u4[0] = r10; a1.u4[1] = r11; a1.u4[2] = r20; a1.u4[3] = r21;
        acc0 = __builtin_amdgcn_mfma_f32_32x32x16_bf16(a0.s, bq[ks], acc0, 0, 0, 0);
        acc1 = __builtin_amdgcn_mfma_f32_32x32x16_bf16(a1.s, bq[ks], acc1, 0, 0, 0);
    }

    // fire(>1) + pool2x2 + pack 30 oc bits -> 3 mask planes of 10 bits
    unsigned int mbase = (unsigned int)((t * 80 + pr) * 80 + wv * 16);
#pragma unroll
    for (int aa = 0; aa < 8; ++aa) {
        bool s = acc0[2 * aa] > 1.f || acc0[2 * aa + 1] > 1.f ||
                 acc1[2 * aa] > 1.f || acc1[2 * aa + 1] > 1.f;
        unsigned long long bal = __ballot(s);
        if (l < 6) {
            int h = l >> 1;
            unsigned int word = (l & 1) ? (unsigned int)(bal >> 32)
                                        : (unsigned int)bal;
            int pc = (aa & 1) + ((aa >> 1) << 2) + ((l & 1) << 1);
            mask1[h * MASK_PLANE + mbase + pc] = (word >> (10 * h)) & 0x3FFu;
        }
    }
}

// ---------------- sparse conv2(3x3) + fire(1.0) + pool3x3 -> pool2m ballot
// block: (t, ph, 9 pw-ninths) = 4860 blocks, 256 thr = 4 waves.
// fp16 oc-pair weights: lane l of oc-half h owns ocs h*128+2l, h*128+2l+1;
// one u32 load = 128 ocs. Wave (h = wv&1, grp = wv>>1): grp0 walks windows
// (pwA, pwA+1) fused; grp1 walks pwA+2 solo (dual-spike).
// v_pk_add_f16 accumulation, UNCONDITIONAL adds: exhausted masks yield
// channel 30 (ctz of the 0x40000000 sentinel) whose w2h rows are zero.
__global__ __launch_bounds__(256) void k_conv2(const unsigned int* __restrict__ mask1,
                                               const unsigned int* __restrict__ w2h,
                                               unsigned long long* __restrict__ pool2m,
                                               unsigned int* __restrict__ flags2) {
    __shared__ unsigned int m_lds[5 * 84];  // rows 3ph-2..3ph+2, cols -2..81

    int b = blockIdx.x;
    int ninth = b % 9;  b /= 9;
    int ph = b % 27;
    int t = b / 27;
    int tid = threadIdx.x;
    int l = tid & 63, wv = tid >> 6;
    int h = wv & 1, grp = wv >> 1;
    int r0 = 3 * ph - 2;
    int pwA = ninth * 3;

    for (int idx = tid; idx < 420; idx += 256) {
        int r = idx / 84, col = idx % 84;
        int gr = r0 + r, gc = col - 2;
        unsigned int v = 0;
        if ((unsigned)gr < 80u && (unsigned)gc < 80u) {
            int i2 = (t * 80 + gr) * 80 + gc;
            v = mask1[i2] | (mask1[MASK_PLANE + i2] << 10) |
                (mask1[2 * MASK_PLANE + i2] << 20);
        }
        m_lds[idx] = v;
    }
    __syncthreads();

    const unsigned int* wb = w2h + h * 64 + l;  // [ck][pl] stride 128
    unsigned long long* prow = pool2m + ((t * 27 + ph) * 27) * 4 + 2 * h;
    __half2 zh = bch2(0u);

    if (grp == 0) {
        // ---- pw pair (pwA, pwA+1): fused walk, unconditional pk_add ----
        int c0A = 3 * pwA, c0B = c0A + 3;
        unsigned int qA[25], qB[25];
#pragma unroll
        for (int dr = 0; dr < 5; ++dr)
#pragma unroll
            for (int ds = 0; ds < 5; ++ds) {
                qA[dr * 5 + ds] = m_lds[dr * 84 + c0A + ds];
                qB[dr * 5 + ds] = m_lds[dr * 84 + c0B + ds];
            }

        __half2 accA[3][3], accB[3][3];
#pragma unroll
        for (int i = 0; i < 3; ++i)
#pragma unroll
            for (int j = 0; j < 3; ++j) { accA[i][j] = zh; accB[i][j] = zh; }

#pragma unroll
        for (int dr = 0; dr < 5; ++dr) {
#pragma unroll
            for (int ds = 0; ds < 5; ++ds) {
                unsigned int mA = qA[dr * 5 + ds];
                unsigned int mB = qB[dr * 5 + ds];
                while (mA | mB) {  // wave-uniform
                    int cA = __builtin_ctz(mA | 0x40000000u);  // empty -> 30
                    int cB = __builtin_ctz(mB | 0x40000000u);
                    mA &= mA - 1;  // 0 stays 0
                    mB &= mB - 1;
                    const unsigned int* pA = wb + cA * 1152;  // c stride 9*128
                    const unsigned int* pB = wb + cB * 1152;
                    unsigned int uA[3][3], uB[3][3];
#pragma unroll
                    for (int i = 0; i < 3; ++i) {
                        if (dr - i < 0 || dr - i > 2) continue;
#pragma unroll
                        for (int j = 0; j < 3; ++j) {
                            if (ds - j < 0 || ds - j > 2) continue;
                            int off = ((dr - i) * 3 + (ds - j)) * 128;
                            uA[i][j] = pA[off];
                            uB[i][j] = pB[off];
                        }
                    }
#pragma unroll
                    for (int i = 0; i < 3; ++i) {
                        if (dr - i < 0 || dr - i > 2) continue;
#pragma unroll
                        for (int j = 0; j < 3; ++j) {
                            if (ds - j < 0 || ds - j > 2) continue;
                            accA[i][j] = __hadd2(accA[i][j], bch2(uA[i][j]));
                            accB[i][j] = __hadd2(accB[i][j], bch2(uB[i][j]));
                        }
                    }
                }
            }
        }

        bool sA0 = false, sA1 = false, sB0 = false, sB1 = false;
#pragma unroll
        for (int i = 0; i < 3; ++i)
#pragma unroll
            for (int j = 0; j < 3; ++j) {
                sA0 = sA0 || (__low2float(accA[i][j])  > 1.f);
                sA1 = sA1 || (__high2float(accA[i][j]) > 1.f);
                sB0 = sB0 || (__low2float(accB[i][j])  > 1.f);
                sB1 = sB1 || (__high2float(accB[i][j]) > 1.f);
            }
        unsigned long long bA0 = __ballot(sA0), bA1 = __ballot(sA1);
        unsigned long long bB0 = __ballot(sB0), bB1 = __ballot(sB1);
        unsigned long long wA0 = expand32((unsigned int)bA0) |
                                 (expand32((unsigned int)bA1) << 1);
        unsigned long long wA1 = expand32((unsigned int)(bA0 >> 32)) |
                                 (expand32((unsigned int)(bA1 >> 32)) << 1);
        unsigned long long wB0 = expand32((unsigned int)bB0) |
                                 (expand32((unsigned int)bB1) << 1);
        unsigned long long wB1 = expand32((unsigned int)(bB0 >> 32)) |
                                 (expand32((unsigned int)(bB1 >> 32)) << 1);
        if (l == 0) {
            prow[pwA * 4]           = wA0;
            prow[pwA * 4 + 1]       = wA1;
            prow[(pwA + 1) * 4]     = wB0;
            prow[(pwA + 1) * 4 + 1] = wB1;
        }
        if ((wA0 | wA1 | wB0 | wB1) && l == 0)
            flags2[t * 27 + ph] = 1u;  // same-value multi-writer
    } else {
        // ---- solo pw (pwA+2), dual-spike walk, unconditional pk_add ----
        int pw = pwA + 2;
        int c0 = 3 * pw;
        unsigned int q[25];
#pragma unroll
        for (int dr = 0; dr < 5; ++dr)
#pragma unroll
            for (int ds = 0; ds < 5; ++ds)
                q[dr * 5 + ds] = m_lds[dr * 84 + c0 + ds];

        __half2 acc[3][3];
#pragma unroll
        for (int i = 0; i < 3; ++i)
#pragma unroll
            for (int j = 0; j < 3; ++j) acc[i][j] = zh;

#pragma unroll
        for (int dr = 0; dr < 5; ++dr) {
#pragma unroll
            for (int ds = 0; ds < 5; ++ds) {
                unsigned int m = q[dr * 5 + ds];
                while (m) {  // wave-uniform
                    int c1 = __builtin_ctz(m); m &= m - 1;
                    int c2 = m ? __builtin_ctz(m) : 30;  // empty -> zero row
                    m &= m - 1;  // 0 stays 0
                    const unsigned int* p1 = wb + c1 * 1152;
                    const unsigned int* p2 = wb + c2 * 1152;
                    unsigned int u1[3][3], u2[3][3];
#pragma unroll
                    for (int i = 0; i < 3; ++i) {
                        if (dr - i < 0 || dr - i > 2) continue;
#pragma unroll
                        for (int j = 0; j < 3; ++j) {
                            if (ds - j < 0 || ds - j > 2) continue;
                            int off = ((dr - i) * 3 + (ds - j)) * 128;
                            u1[i][j] = p1[off];
                            u2[i][j] = p2[off];
                        }
                    }
#pragma unroll
                    for (int i = 0; i < 3; ++i) {
                        if (dr - i < 0 || dr - i > 2) continue;
#pragma unroll
                        for (int j = 0; j < 3; ++j) {
                            if (ds - j < 0 || ds - j > 2) continue;
                            acc[i][j] = __hadd2(acc[i][j], bch2(u1[i][j]));
                            acc[i][j] = __hadd2(acc[i][j], bch2(u2[i][j]));
                        }
                    }
                }
            }
        }

        bool s0 = false, s1 = false;
#pragma unroll
        for (int i = 0; i < 3; ++i)
#pragma unroll
            for (int j = 0; j < 3; ++j) {
                s0 = s0 || (__low2float(acc[i][j])  > 1.f);
                s1 = s1 || (__high2float(acc[i][j]) > 1.f);
            }
        unsigned long long b0 = __ballot(s0), b1 = __ballot(s1);
        unsigned long long w0 = expand32((unsigned int)b0) |
                                (expand32((unsigned int)b1) << 1);
        unsigned long long w1 = expand32((unsigned int)(b0 >> 32)) |
                                (expand32((unsigned int)(b1 >> 32)) << 1);
        if (l == 0) {
            prow[pw * 4]     = w0;
            prow[pw * 4 + 1] = w1;
        }
        if ((w0 | w1) && l == 0) flags2[t * 27 + ph] = 1u;
    }
}

// ---------------- conv3(3x3) + fire(25.0) -> out [spk|pot] (20,200,29,29) x2
__global__ __launch_bounds__(320) void k_conv3(const unsigned long long* __restrict__ pool2m,
                                               const float* __restrict__ w3,
                                               float* __restrict__ out,
                                               const unsigned int* __restrict__ flags2) {
    __shared__ float w_lds[25 * 9 * 40];   // 9000 floats, [ck_local][ocl]
    __shared__ float in_lds[25 * 4 * 34];  // 3400 floats, [cl][r][col]

    int b = blockIdx.x;
    int rb = b % 15;  b /= 15;
    int ocg = b % 5;  b /= 5;
    int t = b;
    int oc0 = ocg * 40;
    int r0 = 2 * rb;  // output rows r0, r0+1
    int tid = threadIdx.x;
    int ocl = tid % 40, ct = tid / 40;  // ct in [0,8)

    // whole-t union of flags (wave-uniform scalar loads)
    {
        unsigned int fT = 0;
        const unsigned int* fp = flags2 + t * 27;
#pragma unroll
        for (int r = 0; r < 27; ++r) fT |= fp[r];
        if (fT == 0) {
            float4 z; z.x = 0.f; z.y = 0.f; z.z = 0.f; z.w = 0.f;
            float4* o0 = (float4*)(out + (size_t)t * T_FLOATS);
            float4* o1 = (float4*)(out + OUT_HALF + (size_t)t * T_FLOATS);
            int s = ocg * 15 + rb;           // slice id 0..74
            int lo = s * 561;                // 75*561 = 42075 >= 42050
            int hi = lo + 561; if (hi > 42050) hi = 42050;
            for (int i = lo + tid; i < hi; i += 320) {
                o0[i] = z;
                o1[i] = z;
            }
            return;
        }
    }

    // receptive field: pool2 rows r0-2..r0+1
    {
        unsigned int f = 0;
        int rlo = r0 - 2; if (rlo < 0) rlo = 0;
        int rhi = r0 + 1; if (rhi > 26) rhi = 26;
        for (int r = rlo; r <= rhi; ++r) f |= flags2[t * 27 + r];
        if (f == 0) {
            int nrows = (r0 + 1 < 29) ? 2 : 1;
            int stride = 29 * nrows;
            int cnt = 40 * stride;
            for (int idx = tid; idx < cnt; idx += 320) {
                int o = idx / stride, rem = idx % stride;
                size_t base = (size_t)((t * 200 + oc0 + o) * 29 + r0) * 29 + rem;
                out[base] = 0.f;
                out[OUT_HALF + base] = 0.f;
            }
            return;
        }
    }

    float acc[2][4];
#pragma unroll
    for (int i = 0; i < 2; ++i)
#pragma unroll
        for (int j = 0; j < 4; ++j) acc[i][j] = 0.f;

    for (int chn = 0; chn < 10; ++chn) {  // channel chunks of 25
        int cc0 = chn * 25;
        for (int idx = tid; idx < 25 * 9 * 40; idx += 320) {
            int o = idx % 40, ck = idx / 40;         // ck in [0,225)
            int ckg = cc0 * 9 + ck;                  // global (c,kh,kw) index
            w_lds[idx] = w3[(size_t)(oc0 + o) * 2250 + ckg];
        }
        for (int idx = tid; idx < 25 * 4 * 34; idx += 320) {
            int col = idx % 34;
            int rem = idx / 34;
            int r = rem & 3, cl = rem >> 2;
            int gr = r0 + r - 2, gc = col - 2;
            float v = 0.f;
            if ((unsigned)gr < 27u && (unsigned)gc < 27u) {
                int c = cc0 + cl;
                unsigned long long wbits =
                    pool2m[((t * 27 + gr) * 27 + gc) * 4 + (c >> 6)];
                v = (float)((wbits >> (c & 63)) & 1ull);
            }
            in_lds[idx] = v;
        }
        __syncthreads();

        for (int cl = 0; cl < 25; ++cl) {
            float in[4][6];
#pragma unroll
            for (int r = 0; r < 4; ++r)
#pragma unroll
                for (int j = 0; j < 6; ++j)
                    in[r][j] = in_lds[(cl * 4 + r) * 34 + ct * 4 + j];
            const float* wp = &w_lds[cl * 360 + ocl];
#pragma unroll
            for (int k = 0; k < 9; ++k) {
                float w = wp[k * 40];
                int kh = k / 3, kw = k % 3;
#pragma unroll
                for (int i = 0; i < 2; ++i)
#pragma unroll
                    for (int j = 0; j < 4; ++j)
                        acc[i][j] += in[i + kh][j + kw] * w;
            }
        }
        __syncthreads();
    }

    {
        int oc = oc0 + ocl;  // always < 200
#pragma unroll
        for (int i = 0; i < 2; ++i) {
            int r = r0 + i;
            if (r < 29) {
#pragma unroll
                for (int j = 0; j < 4; ++j) {
                    int col = ct * 4 + j;
                    if (col < 29) {
                        float pot = acc[i][j];
                        bool s = pot > 25.f;
                        size_t base = ((size_t)((t * 200 + oc) * 29 + r)) * 29 + col;
                        out[base] = s ? 1.f : 0.f;
                        out[OUT_HALF + base] = s ? pot : 0.f;
                    }
                }
            }
        }
    }
}

extern "C" void kernel_launch(void* const* d_in, const int* in_sizes, int n_in,
                              void* d_out, int out_size, void* d_ws, size_t ws_size,
                              hipStream_t stream) {
    const float* x  = (const float*)d_in[0];
    const float* w1 = (const float*)d_in[1];
    const float* w2 = (const float*)d_in[2];
    const float* w3 = (const float*)d_in[3];
    float* out = (float*)d_out;

    // workspace layout (bytes):
    //   mask1  u32: [0, 1,536,000)           3 planes x 20*80*80
    //   pool2m u64: [1,536,000, 2,002,560)   20*27*27*4 x 8B ballot words
    //   w2h    u32: [2,002,560, 2,145,408)   270x128 fp16 pairs + zero pad
    //   flags2    : [2,277,376, +2,160)      u32[20*27]
    unsigned int* mask1 = (unsigned int*)d_ws;
    unsigned long long* pool2m = (unsigned long long*)((char*)d_ws + 1536000);
    unsigned int* w2h = (unsigned int*)((char*)d_ws + 2002560);
    unsigned int* flags2 = (unsigned int*)((char*)d_ws + 2277376);

    // blocks 0..1599: conv1 (LDS-staged MFMA); 1600..1711: w2h pack + flags2
    k_conv1m<<<1712, 320, 0, stream>>>(x, w1, w2, w2h, mask1, flags2);
    k_conv2<<<20 * 27 * 9, 256, 0, stream>>>(mask1, w2h, pool2m, flags2);
    k_conv3<<<20 * 5 * 15, 320, 0, stream>>>(pool2m, w3, out, flags2);
}